// Round 7
// baseline (1675.465 us; speedup 1.0000x reference)
//
#include <hip/hip_runtime.h>
#include <hip/hip_bf16.h>

#define N_NODES 100000
#define N_EDGES 1600000
#define D_IN    128
#define D_HID   512
#define D_OUT   256
#define BKT     64                      // nodes per bucket
#define NB      ((N_NODES + BKT - 1) / BKT)   // 1563 buckets
#define NGRP    8                       // write groups (~XCDs)
#define NCNT    (NB * NGRP)             // 12504 (bucket,group) counters
#define FB      512                     // fill/hist blocks
#define CH      ((N_EDGES + FB - 1) / FB)     // 3125 edges per fill block

typedef __attribute__((ext_vector_type(8))) short bf16x8;
typedef __attribute__((ext_vector_type(4))) float f32x4;
typedef __attribute__((ext_vector_type(8))) unsigned short ushort8;

__device__ __forceinline__ short f2bf(float f) {
  union { float f; unsigned u; } un; un.f = f;
  unsigned r = un.u + 0x7fffu + ((un.u >> 16) & 1u);
  return (short)(r >> 16);
}
__device__ __forceinline__ float bf2f(unsigned short s) {
  union { unsigned u; float f; } un; un.u = ((unsigned)s) << 16; return un.f;
}
__device__ __forceinline__ void load_lds16(const void* g, void* l) {
  __builtin_amdgcn_global_load_lds(
      (const __attribute__((address_space(1))) char*)g,
      (__attribute__((address_space(3))) char*)l, 16, 0, 0);
}

// ---- prep: transpose+convert weights to bf16, zero BN sums + hist ----------
__global__ __launch_bounds__(256) void k_prep(const float* __restrict__ w1,
                                              const float* __restrict__ w2,
                                              short* __restrict__ w1t,
                                              short* __restrict__ w2t,
                                              float* __restrict__ s1,
                                              float* __restrict__ s2,
                                              int* __restrict__ hist) {
  int gid = blockIdx.x * 256 + threadIdx.x;
  if (gid < D_IN * D_HID) {              // w1t[n*128+k] = w1[k*512+n]
    int n = gid >> 7, k = gid & 127;
    w1t[gid] = f2bf(w1[k * D_HID + n]);
  }
  int g2 = gid - D_IN * D_HID;
  if (g2 >= 0 && g2 < D_HID * D_OUT) {   // w2t[n*512+k] = w2[k*256+n]
    int n = g2 >> 9, k = g2 & 511;
    w2t[g2] = f2bf(w2[k * D_OUT + n]);
  }
  if (gid < D_HID) { s1[gid] = 0.f; s2[gid] = 0.f; }
  if (gid < NCNT) hist[gid] = 0;
}

// ---- x -> bf16 -------------------------------------------------------------
__global__ __launch_bounds__(256) void k_xbf(const float* __restrict__ x,
                                             short* __restrict__ xb) {
  int gid = blockIdx.x * 256 + threadIdx.x;
  const int total = N_NODES * D_IN / 4;
  if (gid < total) {
    float4 v = reinterpret_cast<const float4*>(x)[gid];
    short4 o;
    o.x = f2bf(v.x); o.y = f2bf(v.y); o.z = f2bf(v.z); o.w = f2bf(v.w);
    reinterpret_cast<short4*>(xb)[gid] = o;
  }
}

// ---- (bucket,group) histogram: LDS-binned ----------------------------------
__global__ __launch_bounds__(256) void k_bhist(const int* __restrict__ edst,
                                               int* __restrict__ hist) {
  __shared__ int lh[NB];
  int t = threadIdx.x, k = blockIdx.x, g = k & 7;
  for (int i = t; i < NB; i += 256) lh[i] = 0;
  __syncthreads();
  int lim = min((k + 1) * CH, N_EDGES);
  for (int e = k * CH + t; e < lim; e += 256)
    atomicAdd(&lh[edst[e] >> 6], 1);
  __syncthreads();
  for (int i = t; i < NB; i += 256)
    if (lh[i]) atomicAdd(&hist[i * NGRP + g], lh[i]);
}

// ---- scan of NCNT counters (single block, 1024 thr, 16/thread) -------------
__global__ __launch_bounds__(1024) void k_bscan(const int* __restrict__ hist,
                                                int* __restrict__ rp2,
                                                int* __restrict__ cur2) {
  __shared__ int wsum[16];
  int t = threadIdx.x, lane = t & 63, w = t >> 6;
  int v[16];
  int base = t * 16, tsum = 0;
  #pragma unroll
  for (int q = 0; q < 16; ++q) {
    v[q] = (base + q < NCNT) ? hist[base + q] : 0;
    tsum += v[q];
  }
  int sv = tsum;
  #pragma unroll
  for (int off = 1; off < 64; off <<= 1) {
    int u = __shfl_up(sv, off);
    if (lane >= off) sv += u;
  }
  if (lane == 63) wsum[w] = sv;
  __syncthreads();
  if (t < 16) {
    int ws = wsum[t], ss = ws;
    #pragma unroll
    for (int off = 1; off < 16; off <<= 1) {
      int u = __shfl_up(ss, off);
      if (t >= off) ss += u;
    }
    wsum[t] = ss - ws;
  }
  __syncthreads();
  int run = sv - tsum + wsum[w];
  #pragma unroll
  for (int q = 0; q < 16; ++q) {
    if (base + q < NCNT) { rp2[base + q] = run; cur2[base + q] = run; }
    run += v[q];
  }
  if (t == 1023) rp2[NCNT] = run;   // total = N_EDGES
}

// ---- fill bucket-partitioned records; group g fronts fed by one XCD --------
__global__ __launch_bounds__(256) void k_bfill(const int* __restrict__ esrc,
                                               const int* __restrict__ edst,
                                               const float* __restrict__ ew,
                                               int* __restrict__ cur2,
                                               int2* __restrict__ recs) {
  int t = threadIdx.x, k = blockIdx.x, g = k & 7;
  int lim = min((k + 1) * CH, N_EDGES);
  for (int e = k * CH + t; e < lim; e += 256) {
    int d = edst[e];
    int slot = atomicAdd(&cur2[(d >> 6) * NGRP + g], 1);
    int2 r;
    r.x = esrc[e] | ((d & 63) << 20);   // src in bits 0..19, local dst in 20..26
    r.y = __float_as_int(ew[e]);
    recs[slot] = r;
  }
}

// ---- fused aggregate: per-bucket LDS f32 accum, bf16 gather ----------------
__global__ __launch_bounds__(256) void k_aggf(const unsigned short* __restrict__ xb,
                                              const int* __restrict__ rp2,
                                              const int2* __restrict__ recs,
                                              unsigned short* __restrict__ aggb) {
  __shared__ float accf[BKT * D_IN];    // 32 KB
  int t = threadIdx.x, b = blockIdx.x;
  int lane = t & 63, wid = t >> 6;
  // zero accumulator
  #pragma unroll
  for (int i = 0; i < 8; ++i)
    *reinterpret_cast<f32x4*>(&accf[(i * 256 + t) * 4]) = f32x4{0.f, 0.f, 0.f, 0.f};
  __syncthreads();
  int s0 = rp2[b * NGRP], e0 = rp2[b * NGRP + NGRP];
  for (int j = s0 + wid * 64; j < e0; j += 256) {
    int cnt = e0 - j;
    if (cnt > 64) cnt = 64;
    int pk = 0; float wt = 0.f;
    if (lane < cnt) {
      int2 r = recs[j + lane];
      pk = r.x;
      wt = __int_as_float(r.y);
    }
    for (int jj = 0; jj < cnt; ++jj) {
      int p = __shfl(pk, jj);
      float ww = __shfl(wt, jj);
      int s = p & 0xFFFFF;
      int ld = p >> 20;
      ushort2 xv = *reinterpret_cast<const ushort2*>(xb + (size_t)s * D_IN + lane * 2);
      atomicAdd(&accf[ld * D_IN + lane * 2], ww * bf2f(xv.x));
      atomicAdd(&accf[ld * D_IN + lane * 2 + 1], ww * bf2f(xv.y));
    }
  }
  __syncthreads();
  // writeout: acc + (1+eps)*x, bf16
  const float s0c = 1.0f + 1e-9f;
  #pragma unroll
  for (int i = 0; i < 4; ++i) {
    int idx = i * 256 + t;          // 0..1023
    int node = idx >> 4, c8 = (idx & 15) * 8;
    int gnode = b * BKT + node;
    if (gnode < N_NODES) {
      ushort8 xr = *reinterpret_cast<const ushort8*>(xb + (size_t)gnode * D_IN + c8);
      ushort8 o;
      #pragma unroll
      for (int q = 0; q < 8; ++q) {
        float v = accf[node * D_IN + c8 + q] + s0c * bf2f(xr[q]);
        o[q] = (unsigned short)f2bf(v);
      }
      *reinterpret_cast<ushort8*>(aggb + (size_t)gnode * D_IN + c8) = o;
    }
  }
}

// ---- GEMM1: h1 = aggb @ w1 + b1, accumulate BN sums ------------------------
__global__ __launch_bounds__(256) void k_gemm1(const unsigned short* __restrict__ aggb,
                                               const short* __restrict__ w1t,
                                               const float* __restrict__ b1,
                                               short* __restrict__ h1,
                                               float* __restrict__ s1,
                                               float* __restrict__ s2, int M) {
  __shared__ short As[128 * 64];
  __shared__ short Bs[128 * 64];
  int t = threadIdx.x;
  int bid = blockIdx.x;
  int nt = bid & 3, mt = bid >> 2;
  int wid = t >> 6, lane = t & 63;
  int wr = wid >> 1, wc = wid & 1;
  f32x4 acc[4][4] = {};

  for (int kt = 0; kt < 2; ++kt) {
    #pragma unroll
    for (int i = 0; i < 4; ++i) {
      int c = wid * 4 + i;
      int row = c * 8 + (lane >> 3);
      const unsigned short* g = aggb + (size_t)(mt * 128 + row) * D_IN + kt * 64 + (lane & 7) * 8;
      load_lds16(g, As + c * 512);
    }
    #pragma unroll
    for (int i = 0; i < 4; ++i) {
      int c = wid * 4 + i;
      int row = c * 8 + (lane >> 3);
      const short* g = w1t + (size_t)(nt * 128 + row) * D_IN + kt * 64 + (lane & 7) * 8;
      load_lds16(g, Bs + c * 512);
    }
    __syncthreads();
    #pragma unroll
    for (int kk = 0; kk < 2; ++kk) {
      bf16x8 af[4], bfr[4];
      #pragma unroll
      for (int mf = 0; mf < 4; ++mf)
        af[mf] = *reinterpret_cast<const bf16x8*>(As + (wr * 64 + mf * 16 + (lane & 15)) * 64 + kk * 32 + (lane >> 4) * 8);
      #pragma unroll
      for (int nf = 0; nf < 4; ++nf)
        bfr[nf] = *reinterpret_cast<const bf16x8*>(Bs + (wc * 64 + nf * 16 + (lane & 15)) * 64 + kk * 32 + (lane >> 4) * 8);
      #pragma unroll
      for (int mf = 0; mf < 4; ++mf)
        #pragma unroll
        for (int nf = 0; nf < 4; ++nf)
          acc[mf][nf] = __builtin_amdgcn_mfma_f32_16x16x32_bf16(af[mf], bfr[nf], acc[mf][nf], 0, 0, 0);
    }
    __syncthreads();
  }

  int colbase = nt * 128 + wc * 64;
  float ps[4] = {0, 0, 0, 0}, ps2[4] = {0, 0, 0, 0};
  #pragma unroll
  for (int mf = 0; mf < 4; ++mf)
    #pragma unroll
    for (int nf = 0; nf < 4; ++nf) {
      int col = colbase + nf * 16 + (lane & 15);
      float bb = b1[col];
      #pragma unroll
      for (int r = 0; r < 4; ++r) {
        int grow = mt * 128 + wr * 64 + mf * 16 + (lane >> 4) * 4 + r;
        if (grow < M) {
          float v = acc[mf][nf][r] + bb;
          h1[(size_t)grow * D_HID + col] = f2bf(v);
          ps[nf] += v; ps2[nf] += v * v;
        }
      }
    }
  #pragma unroll
  for (int nf = 0; nf < 4; ++nf) {
    float a = ps[nf], b = ps2[nf];
    a += __shfl_xor(a, 16); a += __shfl_xor(a, 32);
    b += __shfl_xor(b, 16); b += __shfl_xor(b, 32);
    if ((lane >> 4) == 0) {
      int col = colbase + nf * 16 + lane;
      unsafeAtomicAdd(&s1[col], a);
      unsafeAtomicAdd(&s2[col], b);
    }
  }
}

// ---- BN params: a = gamma*rsqrt(var+eps), c = beta - mean*a ----------------
__global__ void k_bn(const float* __restrict__ s1, const float* __restrict__ s2,
                     const float* __restrict__ gamma, const float* __restrict__ beta,
                     float* __restrict__ A, float* __restrict__ C) {
  int i = threadIdx.x;
  float inv_n = 1.0f / (float)N_NODES;
  float mean = s1[i] * inv_n;
  float var = s2[i] * inv_n - mean * mean;
  float a = gamma[i] * rsqrtf(var + 1e-5f);
  A[i] = a;
  C[i] = beta[i] - mean * a;
}

// ---- GEMM2: out = relu(h1*a+c) @ w2 + b2 -----------------------------------
__global__ __launch_bounds__(256) void k_gemm2(const unsigned short* __restrict__ h1,
                                               const short* __restrict__ w2t,
                                               const float* __restrict__ b2,
                                               const float* __restrict__ Abn,
                                               const float* __restrict__ Cbn,
                                               float* __restrict__ out, int M) {
  __shared__ short As[128 * 64];
  __shared__ short Bs[128 * 64];
  __shared__ float aL[D_HID], cL[D_HID];
  int t = threadIdx.x;
  for (int i = t; i < D_HID; i += 256) { aL[i] = Abn[i]; cL[i] = Cbn[i]; }
  __syncthreads();

  int bid = blockIdx.x;
  int nt = bid & 1, mt = bid >> 1;
  int wid = t >> 6, lane = t & 63;
  int wr = wid >> 1, wc = wid & 1;
  f32x4 acc[4][4] = {};

  for (int kt = 0; kt < 8; ++kt) {
    #pragma unroll
    for (int i = 0; i < 4; ++i) {
      int idx = i * 2048 + t * 8;
      int row = idx >> 6, k = idx & 63;
      int grow = mt * 128 + row;
      ushort8 res = {};
      if (grow < M) {
        ushort8 u = *reinterpret_cast<const ushort8*>(h1 + (size_t)grow * D_HID + kt * 64 + k);
        #pragma unroll
        for (int j = 0; j < 8; ++j) {
          int gk = kt * 64 + k + j;
          float v = bf2f(u[j]) * aL[gk] + cL[gk];
          v = fmaxf(v, 0.f);
          res[j] = (unsigned short)f2bf(v);
        }
      }
      *reinterpret_cast<ushort8*>(As + idx) = res;
    }
    #pragma unroll
    for (int i = 0; i < 4; ++i) {
      int c = wid * 4 + i;
      int row = c * 8 + (lane >> 3);
      const short* g = w2t + (size_t)(nt * 128 + row) * D_HID + kt * 64 + (lane & 7) * 8;
      load_lds16(g, Bs + c * 512);
    }
    __syncthreads();
    #pragma unroll
    for (int kk = 0; kk < 2; ++kk) {
      bf16x8 af[4], bfr[4];
      #pragma unroll
      for (int mf = 0; mf < 4; ++mf)
        af[mf] = *reinterpret_cast<const bf16x8*>(As + (wr * 64 + mf * 16 + (lane & 15)) * 64 + kk * 32 + (lane >> 4) * 8);
      #pragma unroll
      for (int nf = 0; nf < 4; ++nf)
        bfr[nf] = *reinterpret_cast<const bf16x8*>(Bs + (wc * 64 + nf * 16 + (lane & 15)) * 64 + kk * 32 + (lane >> 4) * 8);
      #pragma unroll
      for (int mf = 0; mf < 4; ++mf)
        #pragma unroll
        for (int nf = 0; nf < 4; ++nf)
          acc[mf][nf] = __builtin_amdgcn_mfma_f32_16x16x32_bf16(af[mf], bfr[nf], acc[mf][nf], 0, 0, 0);
    }
    __syncthreads();
  }

  int colbase = nt * 128 + wc * 64;
  #pragma unroll
  for (int mf = 0; mf < 4; ++mf)
    #pragma unroll
    for (int nf = 0; nf < 4; ++nf) {
      int col = colbase + nf * 16 + (lane & 15);
      float bb = b2[col];
      #pragma unroll
      for (int r = 0; r < 4; ++r) {
        int grow = mt * 128 + wr * 64 + mf * 16 + (lane >> 4) * 4 + r;
        if (grow < M) out[(size_t)grow * D_OUT + col] = acc[mf][nf][r] + bb;
      }
    }
}

extern "C" void kernel_launch(void* const* d_in, const int* in_sizes, int n_in,
                              void* d_out, int out_size, void* d_ws, size_t ws_size,
                              hipStream_t stream) {
  const float* x    = (const float*)d_in[0];
  const int* esrc   = (const int*)d_in[1];
  const int* edst   = (const int*)d_in[2];
  const float* ew   = (const float*)d_in[3];
  const float* w1   = (const float*)d_in[4];
  const float* b1   = (const float*)d_in[5];
  const float* gamma= (const float*)d_in[6];
  const float* beta = (const float*)d_in[7];
  const float* w2   = (const float*)d_in[8];
  const float* b2   = (const float*)d_in[9];
  float* out = (float*)d_out;

  char* base = (char*)d_ws;
  unsigned short* aggb = (unsigned short*)base;                 //  25,600,000 B
  short* h1  = (short*)(base + 25600000);                       // 102,400,000 B
  short* xbf = h1;  // x_bf16 aliases h1: consumed before GEMM1 writes h1
  short* w1t = (short*)(base + 128000000);
  short* w2t = (short*)(base + 128131072);
  float* s1  = (float*)(base + 128393216);
  float* s2  = (float*)(base + 128395264);
  float* Abn = (float*)(base + 128397312);
  float* Cbn = (float*)(base + 128399360);
  int* rp2   = (int*)(base + 128401408);                        // (NCNT+1)*4 = 50,020 B
  int* cur2  = (int*)(base + 128451432);                        // NCNT*4
  int* hist  = (int*)(base + 128501456);                        // NCNT*4
  int2* recs = (int2*)(base + 129000000);                       // E*8 = 12.8 MB

  const int MT = (N_NODES + 127) / 128;  // 782

  k_prep<<<(D_IN * D_HID + D_HID * D_OUT + 255) / 256, 256, 0, stream>>>(w1, w2, w1t, w2t, s1, s2, hist);
  k_xbf<<<(N_NODES * D_IN / 4 + 255) / 256, 256, 0, stream>>>(x, xbf);
  k_bhist<<<FB, 256, 0, stream>>>(edst, hist);
  k_bscan<<<1, 1024, 0, stream>>>(hist, rp2, cur2);
  k_bfill<<<FB, 256, 0, stream>>>(esrc, edst, ew, cur2, recs);
  k_aggf<<<NB, 256, 0, stream>>>((const unsigned short*)xbf, rp2, recs, aggb);
  k_gemm1<<<MT * 4, 256, 0, stream>>>(aggb, w1t, b1, h1, s1, s2, N_NODES);
  k_bn<<<1, D_HID, 0, stream>>>(s1, s2, gamma, beta, Abn, Cbn);
  k_gemm2<<<MT * 2, 256, 0, stream>>>((const unsigned short*)h1, w2t, b2, Abn, Cbn, out, N_NODES);
}